// Round 1
// baseline (319.688 us; speedup 1.0000x reference)
//
#include <hip/hip_runtime.h>
#include <hip/hip_bf16.h>
#include <math.h>

#define HDIM 128
#define INVD 16
#define DIN 272           // 2*H + INV
#define TE 64             // edges per tile
#define NKT 9             // K steps of 32 -> 288 (pad 272->288)
#define LDA 296           // A row stride in bf16 elems (592 B, conflict-free)
#define NWAVE 4

typedef __attribute__((ext_vector_type(4))) float f32x4;
typedef __attribute__((ext_vector_type(4))) float float4v;
typedef __attribute__((ext_vector_type(8))) short bf16x8;
typedef __attribute__((ext_vector_type(4))) short bf16x4;

__device__ inline short f2bf(float f) {
    union { float f; unsigned u; } v; v.f = f;
    unsigned r = v.u + 0x7FFFu + ((v.u >> 16) & 1u);   // RNE
    return (short)(r >> 16);
}

__global__ __launch_bounds__(256) void etnn_kernel(
    const float* __restrict__ x_send,
    const float* __restrict__ x_rec,
    const int*   __restrict__ index,     // [2][E] int32
    const float* __restrict__ edge_attr, // [E][16]
    const float* __restrict__ bn_gamma,
    const float* __restrict__ bn_beta,
    const float* __restrict__ bn_mean,
    const float* __restrict__ bn_var,
    const float* __restrict__ W1,        // [DIN][H]
    const float* __restrict__ b1,        // [H]
    const float* __restrict__ W2,        // [H]
    const float* __restrict__ b2,        // [1]
    float* __restrict__ out,             // [N][H]
    int E)
{
    __shared__ short Atile[TE * LDA];     // 37888 B
    __shared__ float scl[DIN];            // 1088 B
    __shared__ float shf[DIN];            // 1088 B
    __shared__ float pdot[TE][NWAVE];     // 1024 B
    __shared__ float gateL[TE];           // 256 B
    __shared__ int   ridx[TE];            // 256 B

    const int tid = threadIdx.x;
    const int w  = tid >> 6;   // wave id 0..3 -> cols [w*32, w*32+32)
    const int l  = tid & 63;
    const int lr = l & 15;     // row/col within 16
    const int lg = l >> 4;     // k-group 0..3

    // ---- BN constants: scale = gamma*rsqrt(var+eps); shift = beta - mean*scale
    for (int c = tid; c < DIN; c += 256) {
        float sc = bn_gamma[c] * rsqrtf(bn_var[c] + 1e-5f);
        scl[c] = sc;
        shf[c] = bn_beta[c] - bn_mean[c] * sc;
    }
    __syncthreads();

    // ---- Preload W1 as bf16 B-fragments (scale folded in), fold shift into bias
    bf16x8 Bf[NKT][2];
    float biasv[2], w2v[2];
    #pragma unroll
    for (int nt = 0; nt < 2; ++nt) {
        const int col = w * 32 + nt * 16 + lr;
        float bsum = 0.f;
        #pragma unroll
        for (int kk = 0; kk < NKT; ++kk) {
            bf16x8 bv;
            const int kbase = kk * 32 + lg * 8;
            #pragma unroll
            for (int j = 0; j < 8; ++j) {
                const int k = kbase + j;
                float v = 0.f;
                if (k < DIN) {
                    float wv = W1[k * HDIM + col];
                    v = scl[k] * wv;
                    bsum += shf[k] * wv;
                }
                bv[j] = f2bf(v);
            }
            Bf[kk][nt] = bv;
        }
        // reduce partial bias across the 4 k-groups (same col: lanes differ in bits 4..5)
        bsum += __shfl_xor(bsum, 16, 64);
        bsum += __shfl_xor(bsum, 32, 64);
        biasv[nt] = b1[col] + bsum;
        w2v[nt]   = W2[col];
    }
    const float b2v = b2[0];

    const int numTiles = (E + TE - 1) / TE;
    for (int t = blockIdx.x; t < numTiles; t += gridDim.x) {
        __syncthreads();   // protect ridx/gateL/Atile from prev-tile readers
        const int e0 = t * TE;

        // -------- Phase 1: gather + cvt -> LDS A tile --------
        {
            const int r = tid >> 2;       // edge row 0..63
            const int q = tid & 3;        // quarter
            const int e = e0 + r;
            short* arow = &Atile[r * LDA];
            if (e < E) {
                const int is = index[e];
                const int ir = index[E + e];
                if (q == 0) ridx[r] = ir;
                const float4v* ps = (const float4v*)(x_send + (size_t)is * HDIM);
                const float4v* pr = (const float4v*)(x_rec  + (size_t)ir * HDIM);
                #pragma unroll
                for (int i = 0; i < 8; ++i) {
                    float4v v = ps[q + i * 4];
                    bf16x4 o; o[0]=f2bf(v[0]); o[1]=f2bf(v[1]); o[2]=f2bf(v[2]); o[3]=f2bf(v[3]);
                    *(bf16x4*)(arow + (q + i * 4) * 4) = o;
                }
                #pragma unroll
                for (int i = 0; i < 8; ++i) {
                    float4v v = pr[q + i * 4];
                    bf16x4 o; o[0]=f2bf(v[0]); o[1]=f2bf(v[1]); o[2]=f2bf(v[2]); o[3]=f2bf(v[3]);
                    *(bf16x4*)(arow + 128 + (q + i * 4) * 4) = o;
                }
                {
                    float4v v = *(const float4v*)(edge_attr + (size_t)e * INVD + q * 4);
                    bf16x4 o; o[0]=f2bf(v[0]); o[1]=f2bf(v[1]); o[2]=f2bf(v[2]); o[3]=f2bf(v[3]);
                    *(bf16x4*)(arow + 256 + q * 4) = o;
                }
                bf16x4 z = {0, 0, 0, 0};
                *(bf16x4*)(arow + 272 + q * 4) = z;   // K pad 272..287
            } else {
                if (q == 0) ridx[r] = -1;
                bf16x4 z = {0, 0, 0, 0};
                #pragma unroll
                for (int i = 0; i < 18; ++i)          // cols 0..287
                    *(bf16x4*)(arow + q * 4 + i * 16) = z;
            }
        }
        __syncthreads();

        // -------- Phase 2: MFMA  (64 edges) x (272) x (32 cols/wave) --------
        f32x4 acc[4][2];
        #pragma unroll
        for (int mt = 0; mt < 4; ++mt) {
            acc[mt][0] = (f32x4){0.f, 0.f, 0.f, 0.f};
            acc[mt][1] = (f32x4){0.f, 0.f, 0.f, 0.f};
        }
        #pragma unroll
        for (int kk = 0; kk < NKT; ++kk) {
            #pragma unroll
            for (int mt = 0; mt < 4; ++mt) {
                bf16x8 a = *(const bf16x8*)(&Atile[(mt * 16 + lr) * LDA + kk * 32 + lg * 8]);
                acc[mt][0] = __builtin_amdgcn_mfma_f32_16x16x32_bf16(a, Bf[kk][0], acc[mt][0], 0, 0, 0);
                acc[mt][1] = __builtin_amdgcn_mfma_f32_16x16x32_bf16(a, Bf[kk][1], acc[mt][1], 0, 0, 0);
            }
        }

        // -------- Phase 3: SiLU + per-wave partial gate dot --------
        float pd[4][4];
        #pragma unroll
        for (int mt = 0; mt < 4; ++mt) {
            #pragma unroll
            for (int r = 0; r < 4; ++r) {
                float p = 0.f;
                #pragma unroll
                for (int nt = 0; nt < 2; ++nt) {
                    float z = acc[mt][nt][r] + biasv[nt];
                    float m = z / (1.f + __expf(-z));   // SiLU
                    acc[mt][nt][r] = m;
                    p += m * w2v[nt];
                }
                p += __shfl_xor(p, 1, 64);
                p += __shfl_xor(p, 2, 64);
                p += __shfl_xor(p, 4, 64);
                p += __shfl_xor(p, 8, 64);
                pd[mt][r] = p;
            }
        }
        if (lr == 0) {
            #pragma unroll
            for (int mt = 0; mt < 4; ++mt)
                #pragma unroll
                for (int r = 0; r < 4; ++r)
                    pdot[mt * 16 + lg * 4 + r][w] = pd[mt][r];
        }
        __syncthreads();
        if (tid < TE) {
            float s = pdot[tid][0] + pdot[tid][1] + pdot[tid][2] + pdot[tid][3] + b2v;
            gateL[tid] = 1.f / (1.f + __expf(-s));      // sigmoid
        }
        __syncthreads();

        // -------- Phase 4: gated scatter-add --------
        #pragma unroll
        for (int mt = 0; mt < 4; ++mt) {
            #pragma unroll
            for (int r = 0; r < 4; ++r) {
                const int rr = mt * 16 + lg * 4 + r;
                const int node = ridx[rr];
                if (node >= 0) {
                    const float g = gateL[rr];
                    float* orow = out + (size_t)node * HDIM + w * 32 + lr;
                    atomicAdd(orow,      acc[mt][0][r] * g);
                    atomicAdd(orow + 16, acc[mt][1][r] * g);
                }
            }
        }
    }
}

extern "C" void kernel_launch(void* const* d_in, const int* in_sizes, int n_in,
                              void* d_out, int out_size, void* d_ws, size_t ws_size,
                              hipStream_t stream) {
    const float* x_send    = (const float*)d_in[0];
    const float* x_rec     = (const float*)d_in[1];
    const int*   index     = (const int*)d_in[2];
    const float* edge_attr = (const float*)d_in[3];
    const float* bn_gamma  = (const float*)d_in[4];
    const float* bn_beta   = (const float*)d_in[5];
    const float* bn_mean   = (const float*)d_in[6];
    const float* bn_var    = (const float*)d_in[7];
    const float* W1        = (const float*)d_in[8];
    const float* b1        = (const float*)d_in[9];
    const float* W2        = (const float*)d_in[10];
    const float* b2        = (const float*)d_in[11];
    float* out = (float*)d_out;

    const int E = in_sizes[3] / INVD;

    hipMemsetAsync(d_out, 0, (size_t)out_size * sizeof(float), stream);

    const int numTiles = (E + TE - 1) / TE;
    const int grid = numTiles < 768 ? numTiles : 768;
    etnn_kernel<<<grid, 256, 0, stream>>>(x_send, x_rec, index, edge_attr,
                                          bn_gamma, bn_beta, bn_mean, bn_var,
                                          W1, b1, W2, b2, out, E);
}